// Round 6
// baseline (210.075 us; speedup 1.0000x reference)
//
#include <hip/hip_runtime.h>

#define B_  2
#define Q_  2048
#define KV_ 2048
#define D_  1024
#define H_  16
#define DH_ 64

// 0.125 * log2(e): folded into qp so attention scores feed exp2 directly
#define QSCALE 0.18033688011112042f

using u16 = unsigned short;
using bf16x8 = __attribute__((ext_vector_type(8))) short;
using f32x4  = __attribute__((ext_vector_type(4))) float;

__device__ __forceinline__ u16 f2bf(float x) {
  unsigned u = __float_as_uint(x);
  u += 0x7fffu + ((u >> 16) & 1u);   // round-to-nearest-even
  return (u16)(u >> 16);
}

__device__ __forceinline__ void gl_lds16(const void* g, void* l) {
  __builtin_amdgcn_global_load_lds(
      (const __attribute__((address_space(1))) void*)g,
      (__attribute__((address_space(3))) void*)l, 16, 0, 0);
}

#define MFMA16(a, b, c) __builtin_amdgcn_mfma_f32_16x16x32_bf16((a), (b), (c), 0, 0, 0)
#define EXP2F(x) __builtin_amdgcn_exp2f(x)

// ---------------------------------------------------------------------------
// Kernel 1: RMSNorm + bf16 cast for query (rows 0..4095) and key (rows 4096..8191)
// ---------------------------------------------------------------------------
__global__ __launch_bounds__(256) void k_rmsnorm_cast(
    const float* __restrict__ q, const float* __restrict__ k,
    const float* __restrict__ wq, const float* __restrict__ wk,
    u16* __restrict__ qn, u16* __restrict__ kn)
{
  const int row = blockIdx.x;
  const float* src; const float* w; u16* dst;
  if (row < B_ * Q_) {
    src = q + (size_t)row * D_; w = wq; dst = qn + (size_t)row * D_;
  } else {
    const int r2 = row - B_ * Q_;
    src = k + (size_t)r2 * D_; w = wk; dst = kn + (size_t)r2 * D_;
  }
  const int t = threadIdx.x;             // 256 threads, 4 floats each = 1024
  float4 v = reinterpret_cast<const float4*>(src)[t];
  float ss = v.x * v.x + v.y * v.y + v.z * v.z + v.w * v.w;
  #pragma unroll
  for (int off = 1; off < 64; off <<= 1) ss += __shfl_xor(ss, off);
  __shared__ float red[4];
  if ((t & 63) == 0) red[t >> 6] = ss;
  __syncthreads();
  const float tot = red[0] + red[1] + red[2] + red[3];
  const float sc = rsqrtf(tot * (1.0f / D_) + 1.1920929e-07f);
  float4 wv = reinterpret_cast<const float4*>(w)[t];
  ushort4 o;
  o.x = f2bf(v.x * sc * wv.x);
  o.y = f2bf(v.y * sc * wv.y);
  o.z = f2bf(v.z * sc * wv.z);
  o.w = f2bf(v.w * sc * wv.w);
  reinterpret_cast<ushort4*>(dst)[t] = o;
}

// ---------------------------------------------------------------------------
// Kernel 2: small prep — cast Wq|Wk to bf16 (blocks 0..2047) + stage biases
// ---------------------------------------------------------------------------
__global__ __launch_bounds__(256) void k_prep_small(
    const float* __restrict__ Wq, const float* __restrict__ Wk,
    const float* __restrict__ bq, const float* __restrict__ bk,
    u16* __restrict__ Wb, float* __restrict__ biasbuf)
{
  const int bid = blockIdx.x, t = threadIdx.x;
  if (bid < 2048) {
    const int i = bid * 256 + t;               // 0..524287 float4s
    const bool isK = i >= 262144;
    const int j = i & 262143;                  // index within one 1Mx float matrix
    float4 v = reinterpret_cast<const float4*>(isK ? Wk : Wq)[j];
    ushort4 o;
    o.x = f2bf(v.x); o.y = f2bf(v.y); o.z = f2bf(v.z); o.w = f2bf(v.w);
    reinterpret_cast<ushort4*>(Wb + (isK ? D_ * D_ : 0))[j] = o;
  } else {
    #pragma unroll
    for (int r = 0; r < 2; ++r) {
      const int i = r * 256 + t;               // 0..511 float4s (2048 floats)
      float4 v = (i < 256) ? reinterpret_cast<const float4*>(bq)[i]
                           : reinterpret_cast<const float4*>(bk)[i - 256];
      reinterpret_cast<float4*>(biasbuf)[i] = v;
    }
  }
}

// ---------------------------------------------------------------------------
// Kernel 3: value (B,KV,D) fp32 -> vT (B,D,KV) bf16, 64x64 LDS tiles
// ---------------------------------------------------------------------------
__global__ __launch_bounds__(256) void k_transpose_cast_v(
    const float* __restrict__ v, u16* __restrict__ vT)
{
  const int kv0 = blockIdx.x * 64, d0 = blockIdx.y * 64, b = blockIdx.z;
  __shared__ u16 tile[64][72];           // +8 pad breaks bank conflicts
  const int t = threadIdx.x;
  #pragma unroll
  for (int i = 0; i < 16; ++i) {
    const int idx = i * 256 + t, r = idx >> 6, c = idx & 63;
    tile[r][c] = f2bf(v[((size_t)b * KV_ + kv0 + r) * D_ + d0 + c]);
  }
  __syncthreads();
  #pragma unroll
  for (int i = 0; i < 16; ++i) {
    const int idx = i * 256 + t, r = idx >> 6, c = idx & 63;
    vT[((size_t)b * D_ + d0 + r) * KV_ + kv0 + c] = tile[c][r];
  }
}

// ---------------------------------------------------------------------------
// Kernel 4: C = A * B^T (+bias,*scale), bf16 in, fp32 accum. TM x TN tile,
// BK=64, 4 waves as 2x2, T2-swizzled LDS, double-buffered 2-phase pipeline.
// ---------------------------------------------------------------------------
__device__ __forceinline__ int swz_off(int row, int unit) {
  return row * 64 + ((unit ^ (row & 7)) << 3);
}

template<int TM, int TN, bool OUT_BF16, bool PROJ>
__global__ __launch_bounds__(256) void k_gemm_bt(
    const u16* __restrict__ A, int lda, long sA,
    const u16* __restrict__ Bm, int ldb, long sB,
    void* __restrict__ C, int ldc, long sC,
    int K, const float* __restrict__ bias)
{
  constexpr int MR = TM / 32, NR = TN / 32;    // per-wave 16x16 frag repeats
  const int bb = blockIdx.z;
  const u16* Ab = A + (size_t)bb * sA;
  const u16* Bb = Bm + (size_t)bb * sB;
  const int row0 = blockIdx.y * TM, col0 = blockIdx.x * TN;
  __shared__ u16 As[2][TM * 64];
  __shared__ u16 Bs[2][TN * 64];
  const int tid = threadIdx.x, lane = tid & 63;
  const int w = tid >> 6, wm = w >> 1, wn = w & 1;
  const int lrow = lane & 15, sub = lane >> 4, lrow7 = lrow & 7;
  const f32x4 zero4 = {0.f, 0.f, 0.f, 0.f};
  f32x4 acc[MR][NR];
  #pragma unroll
  for (int m = 0; m < MR; ++m)
    #pragma unroll
    for (int n = 0; n < NR; ++n) acc[m][n] = zero4;

  const int nk = K >> 6;

#define GEMM_STAGE(buf, kt)                                                   \
  {                                                                           \
    const int k0 = (kt) << 6;                                                 \
    _Pragma("unroll")                                                         \
    for (int i = 0; i < TM / 32; ++i) {                                       \
      const int c = i * 256 + tid, r = c >> 3, u = (c & 7) ^ (r & 7);         \
      gl_lds16(Ab + (size_t)(row0 + r) * lda + k0 + u * 8, &As[buf][c * 8]);  \
    }                                                                         \
    _Pragma("unroll")                                                         \
    for (int i = 0; i < TN / 32; ++i) {                                       \
      const int c = i * 256 + tid, r = c >> 3, u = (c & 7) ^ (r & 7);         \
      gl_lds16(Bb + (size_t)(col0 + r) * ldb + k0 + u * 8, &Bs[buf][c * 8]);  \
    }                                                                         \
  }

  GEMM_STAGE(0, 0);
  int cur = 0;
  for (int kt = 0; kt < nk; ++kt) {
    __syncthreads();                       // drains vmcnt: buf[cur] ready
    if (kt + 1 < nk) GEMM_STAGE(cur ^ 1, kt + 1);
    #pragma unroll
    for (int ks = 0; ks < 2; ++ks) {
      bf16x8 af[MR], bfr[NR];
      #pragma unroll
      for (int m = 0; m < MR; ++m) {
        const int rA = wm * (TM / 2) + m * 16 + lrow;
        af[m] = *(const bf16x8*)&As[cur][rA * 64 + ((((ks << 2) + sub) ^ lrow7) << 3)];
      }
      #pragma unroll
      for (int n = 0; n < NR; ++n) {
        const int rB = wn * (TN / 2) + n * 16 + lrow;
        bfr[n] = *(const bf16x8*)&Bs[cur][rB * 64 + ((((ks << 2) + sub) ^ lrow7) << 3)];
      }
      #pragma unroll
      for (int m = 0; m < MR; ++m)
        #pragma unroll
        for (int n = 0; n < NR; ++n)
          acc[m][n] = MFMA16(af[m], bfr[n], acc[m][n]);
    }
    cur ^= 1;
  }
#undef GEMM_STAGE

  const int crow = sub * 4, ccol = lane & 15;
  const float scl = (PROJ && bb == 0) ? QSCALE : 1.0f;
  #pragma unroll
  for (int m = 0; m < MR; ++m) {
    #pragma unroll
    for (int n = 0; n < NR; ++n) {
      const int gcol = col0 + wn * (TN / 2) + n * 16 + ccol;
      const float badd = PROJ ? bias[bb * 1024 + gcol] : 0.0f;
      #pragma unroll
      for (int r = 0; r < 4; ++r) {
        const int grow = row0 + wm * (TM / 2) + m * 16 + crow + r;
        const float val = (acc[m][n][r] + badd) * scl;
        if (OUT_BF16)
          ((u16*)C)[(size_t)bb * sC + (size_t)grow * ldc + gcol] = f2bf(val);
        else
          ((float*)C)[(size_t)bb * sC + (size_t)grow * ldc + gcol] = val;
      }
    }
  }
}

// ---------------------------------------------------------------------------
// Kernel 5 (pass A): Linv[b,h,i] = 1 / (H * sum_j 2^s(i,j))   (qp pre-scaled)
// block = (64 q-rows, head, batch), NO LDS staging, NO per-tile barriers:
// wave w reads its K fragments directly from global (L2-resident, 8 MB),
// covering kv stripe {w*32 + 128*t}. q-frags hoisted (h fixed per block).
// One barrier at the end for the cross-wave reduction.
// ---------------------------------------------------------------------------
__global__ __launch_bounds__(256, 4) void k_attn_rowsum(
    const u16* __restrict__ qp, const u16* __restrict__ kp,
    float* __restrict__ Linv)
{
  const int qb = blockIdx.x * 64, h = blockIdx.y, b = blockIdx.z;
  __shared__ float red[4][64];
  const int tid = threadIdx.x, lane = tid & 63, w = tid >> 6;
  const int lrow = lane & 15, sub = lane >> 4;

  const u16* qbase = qp + ((size_t)b * Q_ + qb) * D_ + h * 64;
  const u16* kbase = kp + ((size_t)b * KV_ + w * 32) * D_ + h * 64;

  // q fragments for all 64 q-rows (loop-invariant: h fixed per block)
  bf16x8 af[4][2];
  #pragma unroll
  for (int m = 0; m < 4; ++m)
    #pragma unroll
    for (int ks = 0; ks < 2; ++ks)
      af[m][ks] = *(const bf16x8*)&qbase[(m * 16 + lrow) * D_ + ks * 32 + sub * 8];

  const f32x4 zero4 = {0.f, 0.f, 0.f, 0.f};
  float lsum[4][4];
  #pragma unroll
  for (int m = 0; m < 4; ++m)
    #pragma unroll
    for (int r = 0; r < 4; ++r) lsum[m][r] = 0.f;

  for (int t = 0; t < KV_ / 128; ++t) {
    bf16x8 bk[2][2];
    #pragma unroll
    for (int n = 0; n < 2; ++n)
      #pragma unroll
      for (int ks = 0; ks < 2; ++ks)
        bk[n][ks] = *(const bf16x8*)&kbase[((size_t)t * 128 + n * 16 + lrow) * D_
                                           + ks * 32 + sub * 8];
    #pragma unroll
    for (int n = 0; n < 2; ++n) {
      #pragma unroll
      for (int m = 0; m < 4; ++m) {
        f32x4 s = zero4;
        s = MFMA16(af[m][0], bk[n][0], s);
        s = MFMA16(af[m][1], bk[n][1], s);
        #pragma unroll
        for (int r = 0; r < 4; ++r) lsum[m][r] += EXP2F(s[r]);
      }
    }
  }
  // reduce over the 16 kv-columns held within each 16-lane group
  #pragma unroll
  for (int m = 0; m < 4; ++m)
    #pragma unroll
    for (int r = 0; r < 4; ++r) {
      #pragma unroll
      for (int off = 1; off < 16; off <<= 1)
        lsum[m][r] += __shfl_xor(lsum[m][r], off);
    }
  if (lrow == 0) {
    #pragma unroll
    for (int m = 0; m < 4; ++m)
      #pragma unroll
      for (int r = 0; r < 4; ++r) red[w][m * 16 + sub * 4 + r] = lsum[m][r];
  }
  __syncthreads();
  if (tid < 64) {
    const float s = red[0][tid] + red[1][tid] + red[2][tid] + red[3][tid];
    Linv[((size_t)b * H_ + h) * Q_ + qb + tid] = 1.0f / (s * (float)H_);
  }
}

// ---------------------------------------------------------------------------
// Kernel 6 (pass B): attn[b,i,j] = sum_h 2^s_h(i,j) * Linv[b,h,i]
// block = (64 q-rows, 128 kv-cols, batch); wave w owns 64q x 32kv. NO LDS,
// NO barriers: K/q/Linv fragments loaded directly from global (L2-resident)
// each head. Waves fully independent -> TLP hides all memory latency.
// ---------------------------------------------------------------------------
__global__ __launch_bounds__(256, 3) void k_attn_weights(
    const u16* __restrict__ qp, const u16* __restrict__ kp,
    const float* __restrict__ Linv, u16* __restrict__ attn)
{
  const int kv0 = blockIdx.x * 128, qb = blockIdx.y * 64, b = blockIdx.z;
  const int tid = threadIdx.x, lane = tid & 63, w = tid >> 6;
  const int lrow = lane & 15, sub = lane >> 4;
  const int kvw = kv0 + w * 32;          // this wave's 32 kv rows

  const u16* qbase = qp + ((size_t)b * Q_ + qb) * D_;
  const u16* kbase = kp + ((size_t)b * KV_ + kvw) * D_;
  const float* lbase = Linv + (size_t)b * H_ * Q_ + qb;

  const f32x4 zero4 = {0.f, 0.f, 0.f, 0.f};
  f32x4 acc[4][2];                       // m: 4x16 q-rows, n: 2x16 kv-cols
  #pragma unroll
  for (int m = 0; m < 4; ++m)
    #pragma unroll
    for (int n = 0; n < 2; ++n) acc[m][n] = zero4;

  for (int h = 0; h < H_; ++h) {
    bf16x8 af[4][2], bk[2][2];
    #pragma unroll
    for (int m = 0; m < 4; ++m)
      #pragma unroll
      for (int ks = 0; ks < 2; ++ks)
        af[m][ks] = *(const bf16x8*)&qbase[(m * 16 + lrow) * D_ + h * 64
                                           + ks * 32 + sub * 8];
    #pragma unroll
    for (int n = 0; n < 2; ++n)
      #pragma unroll
      for (int ks = 0; ks < 2; ++ks)
        bk[n][ks] = *(const bf16x8*)&kbase[(n * 16 + lrow) * D_ + h * 64
                                           + ks * 32 + sub * 8];
    f32x4 lv[4];
    #pragma unroll
    for (int m = 0; m < 4; ++m)
      lv[m] = *(const f32x4*)&lbase[(size_t)h * Q_ + m * 16 + sub * 4];
    #pragma unroll
    for (int m = 0; m < 4; ++m) {
      #pragma unroll
      for (int n = 0; n < 2; ++n) {
        f32x4 s = zero4;
        s = MFMA16(af[m][0], bk[n][0], s);
        s = MFMA16(af[m][1], bk[n][1], s);
        #pragma unroll
        for (int r = 0; r < 4; ++r)
          acc[m][n][r] += EXP2F(s[r]) * lv[m][r];
      }
    }
  }
  #pragma unroll
  for (int m = 0; m < 4; ++m) {
    #pragma unroll
    for (int n = 0; n < 2; ++n) {
      const int gcol = kvw + n * 16 + lrow;
      #pragma unroll
      for (int r = 0; r < 4; ++r) {
        const int grow = qb + m * 16 + sub * 4 + r;
        attn[((size_t)b * Q_ + grow) * KV_ + gcol] = f2bf(acc[m][n][r]);
      }
    }
  }
}

// ---------------------------------------------------------------------------
// Launch
// ---------------------------------------------------------------------------
extern "C" void kernel_launch(void* const* d_in, const int* in_sizes, int n_in,
                              void* d_out, int out_size, void* d_ws, size_t ws_size,
                              hipStream_t stream)
{
  (void)in_sizes; (void)n_in; (void)out_size; (void)ws_size;
  const float* query = (const float*)d_in[0];
  const float* key   = (const float*)d_in[1];
  const float* value = (const float*)d_in[2];
  const float* wqn   = (const float*)d_in[3];
  const float* wkn   = (const float*)d_in[4];
  const float* Wq    = (const float*)d_in[5];
  const float* Wk    = (const float*)d_in[6];
  const float* bq    = (const float*)d_in[7];
  const float* bk    = (const float*)d_in[8];
  float* out = (float*)d_out;

  // workspace layout (~46.7 MB; attn aliases the dead qn+kn region)
  char* ws = (char*)d_ws;
  u16* qn   = (u16*)(ws);                 //  8 MiB  (B*Q, D)  bf16
  u16* attn = (u16*)(ws);                 // 16 MiB  (B, Q, KV) bf16 — alias qn+kn
  u16* qp   = (u16*)(ws + 16777216);      //  8 MiB  (B*Q, D)  bf16
  u16* kp   = (u16*)(ws + 25165824);      //  8 MiB  (B*KV, D) bf16
  u16* Wqb  = (u16*)(ws + 33554432);      //  4 MiB  (2, D, D) bf16 (Wq|Wk adjacent)
  u16* vT   = (u16*)(ws + 37748736);      //  8 MiB  (B, D, KV) bf16
  float* Linv = (float*)(ws + 46137344);  // 256 KiB (B, H, Q) fp32
  float* biasbuf = (float*)(ws + 46399488); // 8 KiB (2, D) fp32
  u16* kn = qn + 4194304;

  k_rmsnorm_cast<<<dim3(B_ * Q_ + B_ * KV_), dim3(256), 0, stream>>>(
      query, key, wqn, wkn, qn, kn);
  k_prep_small<<<dim3(2049), dim3(256), 0, stream>>>(Wq, Wk, bq, bk, Wqb, biasbuf);
  k_transpose_cast_v<<<dim3(KV_ / 64, D_ / 64, B_), dim3(256), 0, stream>>>(value, vT);

  // batched projections: z=0 -> qp = (qn@Wq^T + bq)*QSCALE ; z=1 -> kp = kn@Wk^T + bk
  k_gemm_bt<128, 128, true, true>
      <<<dim3(D_ / 128, (B_ * Q_) / 128, 2), dim3(256), 0, stream>>>(
      qn, D_, 4194304, Wqb, D_, 1048576, qp, D_, 4194304, D_, biasbuf);

  k_attn_rowsum<<<dim3(Q_ / 64, H_, B_), dim3(256), 0, stream>>>(qp, kp, Linv);
  k_attn_weights<<<dim3(KV_ / 128, Q_ / 64, B_), dim3(256), 0, stream>>>(qp, kp, Linv, attn);

  // PV: out[b] = attn[b] @ vT[b]^T, 128x64 tiles -> 512 blocks (2/CU)
  k_gemm_bt<128, 64, false, false>
      <<<dim3(D_ / 64, Q_ / 128, B_), dim3(256), 0, stream>>>(
      attn, KV_, (long)Q_ * KV_, vT, KV_, (long)D_ * KV_,
      out, D_, (long)Q_ * D_, KV_, nullptr);
}

// Round 7
// 139.165 us; speedup vs baseline: 1.5095x; 1.5095x over previous
//
#include <hip/hip_runtime.h>

#define B_  2
#define Q_  2048
#define KV_ 2048
#define D_  1024
#define H_  16
#define DH_ 64

// 0.125 * log2(e): folded into qp so attention scores feed exp2 directly
#define QSCALE 0.18033688011112042f

using u16 = unsigned short;
using bf16x8 = __attribute__((ext_vector_type(8))) short;
using f32x4  = __attribute__((ext_vector_type(4))) float;

__device__ __forceinline__ u16 f2bf(float x) {
  unsigned u = __float_as_uint(x);
  u += 0x7fffu + ((u >> 16) & 1u);   // round-to-nearest-even
  return (u16)(u >> 16);
}

__device__ __forceinline__ void gl_lds16(const void* g, void* l) {
  __builtin_amdgcn_global_load_lds(
      (const __attribute__((address_space(1))) void*)g,
      (__attribute__((address_space(3))) void*)l, 16, 0, 0);
}

#define MFMA16(a, b, c) __builtin_amdgcn_mfma_f32_16x16x32_bf16((a), (b), (c), 0, 0, 0)
#define EXP2F(x) __builtin_amdgcn_exp2f(x)

// ---------------------------------------------------------------------------
// Kernel 1: RMSNorm + bf16 cast for query (rows 0..4095) and key (rows 4096..8191)
// ---------------------------------------------------------------------------
__global__ __launch_bounds__(256) void k_rmsnorm_cast(
    const float* __restrict__ q, const float* __restrict__ k,
    const float* __restrict__ wq, const float* __restrict__ wk,
    u16* __restrict__ qn, u16* __restrict__ kn)
{
  const int row = blockIdx.x;
  const float* src; const float* w; u16* dst;
  if (row < B_ * Q_) {
    src = q + (size_t)row * D_; w = wq; dst = qn + (size_t)row * D_;
  } else {
    const int r2 = row - B_ * Q_;
    src = k + (size_t)r2 * D_; w = wk; dst = kn + (size_t)r2 * D_;
  }
  const int t = threadIdx.x;             // 256 threads, 4 floats each = 1024
  float4 v = reinterpret_cast<const float4*>(src)[t];
  float ss = v.x * v.x + v.y * v.y + v.z * v.z + v.w * v.w;
  #pragma unroll
  for (int off = 1; off < 64; off <<= 1) ss += __shfl_xor(ss, off);
  __shared__ float red[4];
  if ((t & 63) == 0) red[t >> 6] = ss;
  __syncthreads();
  const float tot = red[0] + red[1] + red[2] + red[3];
  const float sc = rsqrtf(tot * (1.0f / D_) + 1.1920929e-07f);
  float4 wv = reinterpret_cast<const float4*>(w)[t];
  ushort4 o;
  o.x = f2bf(v.x * sc * wv.x);
  o.y = f2bf(v.y * sc * wv.y);
  o.z = f2bf(v.z * sc * wv.z);
  o.w = f2bf(v.w * sc * wv.w);
  reinterpret_cast<ushort4*>(dst)[t] = o;
}

// ---------------------------------------------------------------------------
// Kernel 2: small prep — cast Wq|Wk to bf16 (blocks 0..2047) + stage biases
// ---------------------------------------------------------------------------
__global__ __launch_bounds__(256) void k_prep_small(
    const float* __restrict__ Wq, const float* __restrict__ Wk,
    const float* __restrict__ bq, const float* __restrict__ bk,
    u16* __restrict__ Wb, float* __restrict__ biasbuf)
{
  const int bid = blockIdx.x, t = threadIdx.x;
  if (bid < 2048) {
    const int i = bid * 256 + t;               // 0..524287 float4s
    const bool isK = i >= 262144;
    const int j = i & 262143;                  // index within one 1Mx float matrix
    float4 v = reinterpret_cast<const float4*>(isK ? Wk : Wq)[j];
    ushort4 o;
    o.x = f2bf(v.x); o.y = f2bf(v.y); o.z = f2bf(v.z); o.w = f2bf(v.w);
    reinterpret_cast<ushort4*>(Wb + (isK ? D_ * D_ : 0))[j] = o;
  } else {
    #pragma unroll
    for (int r = 0; r < 2; ++r) {
      const int i = r * 256 + t;               // 0..511 float4s (2048 floats)
      float4 v = (i < 256) ? reinterpret_cast<const float4*>(bq)[i]
                           : reinterpret_cast<const float4*>(bk)[i - 256];
      reinterpret_cast<float4*>(biasbuf)[i] = v;
    }
  }
}

// ---------------------------------------------------------------------------
// Kernel 3: value (B,KV,D) fp32 -> vT (B,D,KV) bf16, 64x64 LDS tiles
// ---------------------------------------------------------------------------
__global__ __launch_bounds__(256) void k_transpose_cast_v(
    const float* __restrict__ v, u16* __restrict__ vT)
{
  const int kv0 = blockIdx.x * 64, d0 = blockIdx.y * 64, b = blockIdx.z;
  __shared__ u16 tile[64][72];           // +8 pad breaks bank conflicts
  const int t = threadIdx.x;
  #pragma unroll
  for (int i = 0; i < 16; ++i) {
    const int idx = i * 256 + t, r = idx >> 6, c = idx & 63;
    tile[r][c] = f2bf(v[((size_t)b * KV_ + kv0 + r) * D_ + d0 + c]);
  }
  __syncthreads();
  #pragma unroll
  for (int i = 0; i < 16; ++i) {
    const int idx = i * 256 + t, r = idx >> 6, c = idx & 63;
    vT[((size_t)b * D_ + d0 + r) * KV_ + kv0 + c] = tile[c][r];
  }
}

// ---------------------------------------------------------------------------
// Kernel 4: C = A * B^T (+bias,*scale), bf16 in, fp32 accum. TM x TN tile,
// BK=64, 4 waves as 2x2, T2-swizzled LDS, double-buffered 2-phase pipeline.
// ---------------------------------------------------------------------------
__device__ __forceinline__ int swz_off(int row, int unit) {
  return row * 64 + ((unit ^ (row & 7)) << 3);
}

template<int TM, int TN, bool OUT_BF16, bool PROJ>
__global__ __launch_bounds__(256) void k_gemm_bt(
    const u16* __restrict__ A, int lda, long sA,
    const u16* __restrict__ Bm, int ldb, long sB,
    void* __restrict__ C, int ldc, long sC,
    int K, const float* __restrict__ bias)
{
  constexpr int MR = TM / 32, NR = TN / 32;    // per-wave 16x16 frag repeats
  const int bb = blockIdx.z;
  const u16* Ab = A + (size_t)bb * sA;
  const u16* Bb = Bm + (size_t)bb * sB;
  const int row0 = blockIdx.y * TM, col0 = blockIdx.x * TN;
  __shared__ u16 As[2][TM * 64];
  __shared__ u16 Bs[2][TN * 64];
  const int tid = threadIdx.x, lane = tid & 63;
  const int w = tid >> 6, wm = w >> 1, wn = w & 1;
  const int lrow = lane & 15, sub = lane >> 4, lrow7 = lrow & 7;
  const f32x4 zero4 = {0.f, 0.f, 0.f, 0.f};
  f32x4 acc[MR][NR];
  #pragma unroll
  for (int m = 0; m < MR; ++m)
    #pragma unroll
    for (int n = 0; n < NR; ++n) acc[m][n] = zero4;

  const int nk = K >> 6;

#define GEMM_STAGE(buf, kt)                                                   \
  {                                                                           \
    const int k0 = (kt) << 6;                                                 \
    _Pragma("unroll")                                                         \
    for (int i = 0; i < TM / 32; ++i) {                                       \
      const int c = i * 256 + tid, r = c >> 3, u = (c & 7) ^ (r & 7);         \
      gl_lds16(Ab + (size_t)(row0 + r) * lda + k0 + u * 8, &As[buf][c * 8]);  \
    }                                                                         \
    _Pragma("unroll")                                                         \
    for (int i = 0; i < TN / 32; ++i) {                                       \
      const int c = i * 256 + tid, r = c >> 3, u = (c & 7) ^ (r & 7);         \
      gl_lds16(Bb + (size_t)(col0 + r) * ldb + k0 + u * 8, &Bs[buf][c * 8]);  \
    }                                                                         \
  }

  GEMM_STAGE(0, 0);
  int cur = 0;
  for (int kt = 0; kt < nk; ++kt) {
    __syncthreads();                       // drains vmcnt: buf[cur] ready
    if (kt + 1 < nk) GEMM_STAGE(cur ^ 1, kt + 1);
    #pragma unroll
    for (int ks = 0; ks < 2; ++ks) {
      bf16x8 af[MR], bfr[NR];
      #pragma unroll
      for (int m = 0; m < MR; ++m) {
        const int rA = wm * (TM / 2) + m * 16 + lrow;
        af[m] = *(const bf16x8*)&As[cur][rA * 64 + ((((ks << 2) + sub) ^ lrow7) << 3)];
      }
      #pragma unroll
      for (int n = 0; n < NR; ++n) {
        const int rB = wn * (TN / 2) + n * 16 + lrow;
        bfr[n] = *(const bf16x8*)&Bs[cur][rB * 64 + ((((ks << 2) + sub) ^ lrow7) << 3)];
      }
      #pragma unroll
      for (int m = 0; m < MR; ++m)
        #pragma unroll
        for (int n = 0; n < NR; ++n)
          acc[m][n] = MFMA16(af[m], bfr[n], acc[m][n]);
    }
    cur ^= 1;
  }
#undef GEMM_STAGE

  const int crow = sub * 4, ccol = lane & 15;
  const float scl = (PROJ && bb == 0) ? QSCALE : 1.0f;
  #pragma unroll
  for (int m = 0; m < MR; ++m) {
    #pragma unroll
    for (int n = 0; n < NR; ++n) {
      const int gcol = col0 + wn * (TN / 2) + n * 16 + ccol;
      const float badd = PROJ ? bias[bb * 1024 + gcol] : 0.0f;
      #pragma unroll
      for (int r = 0; r < 4; ++r) {
        const int grow = row0 + wm * (TM / 2) + m * 16 + crow + r;
        const float val = (acc[m][n][r] + badd) * scl;
        if (OUT_BF16)
          ((u16*)C)[(size_t)bb * sC + (size_t)grow * ldc + gcol] = f2bf(val);
        else
          ((float*)C)[(size_t)bb * sC + (size_t)grow * ldc + gcol] = val;
      }
    }
  }
}

// ---------------------------------------------------------------------------
// Kernel 5 (pass A): Linv[b,h,i] = 1 / (H * sum_j 2^s(i,j))   (qp pre-scaled)
// GEMM-style: block = (128 q-rows, head, batch), 4 waves 2x2 (64q x 64kv).
// Aq staged once; K tiles double-buffered (2-phase); in-register row partials,
// 16-lane shuffle reduce + tiny LDS cross-wave reduce at the end.
// ---------------------------------------------------------------------------
__global__ __launch_bounds__(256) void k_attn_rowsum(
    const u16* __restrict__ qp, const u16* __restrict__ kp,
    float* __restrict__ Linv)
{
  const int qb = blockIdx.x * 128, h = blockIdx.y, b = blockIdx.z;
  __shared__ u16 Aq[128 * 64];
  __shared__ u16 Kk[2][128 * 64];
  __shared__ float red[2][128];
  const int tid = threadIdx.x, lane = tid & 63, w = tid >> 6;
  const int wm = w >> 1, wn = w & 1;
  const int lrow = lane & 15, sub = lane >> 4, lrow7 = lrow & 7;

  // stage Aq once (swizzled source)
  #pragma unroll
  for (int i = 0; i < 4; ++i) {
    const int c = i * 256 + tid, r = c >> 3, u = (c & 7) ^ (r & 7);
    gl_lds16(&qp[((size_t)b * Q_ + qb + r) * D_ + h * 64 + u * 8], &Aq[c * 8]);
  }

#define STAGE_KK(buf, kvt)                                                    \
  {                                                                           \
    _Pragma("unroll")                                                         \
    for (int i = 0; i < 4; ++i) {                                             \
      const int c = i * 256 + tid, r = c >> 3, u = (c & 7) ^ (r & 7);         \
      gl_lds16(&kp[((size_t)b * KV_ + (kvt) * 128 + r) * D_ + h * 64 + u * 8],\
               &Kk[buf][c * 8]);                                              \
    }                                                                         \
  }

  STAGE_KK(0, 0);
  const f32x4 zero4 = {0.f, 0.f, 0.f, 0.f};
  float lsum[4][4];
  #pragma unroll
  for (int m = 0; m < 4; ++m)
    #pragma unroll
    for (int r = 0; r < 4; ++r) lsum[m][r] = 0.f;
  bf16x8 af[4][2];

  for (int kvt = 0; kvt < KV_ / 128; ++kvt) {
    const int cur = kvt & 1;
    __syncthreads();
    if (kvt == 0) {
      #pragma unroll
      for (int m = 0; m < 4; ++m) {
        const int rA = wm * 64 + m * 16 + lrow;
        af[m][0] = *(const bf16x8*)&Aq[rA * 64 + ((sub ^ lrow7) << 3)];
        af[m][1] = *(const bf16x8*)&Aq[rA * 64 + (((4 + sub) ^ lrow7) << 3)];
      }
    }
    if (kvt + 1 < KV_ / 128) STAGE_KK(cur ^ 1, kvt + 1);
    bf16x8 bf[4][2];
    #pragma unroll
    for (int n = 0; n < 4; ++n) {
      const int rB = wn * 64 + n * 16 + lrow;
      bf[n][0] = *(const bf16x8*)&Kk[cur][rB * 64 + ((sub ^ lrow7) << 3)];
      bf[n][1] = *(const bf16x8*)&Kk[cur][rB * 64 + (((4 + sub) ^ lrow7) << 3)];
    }
    #pragma unroll
    for (int m = 0; m < 4; ++m) {
      #pragma unroll
      for (int n = 0; n < 4; ++n) {
        f32x4 s = zero4;
        s = MFMA16(af[m][0], bf[n][0], s);
        s = MFMA16(af[m][1], bf[n][1], s);
        #pragma unroll
        for (int r = 0; r < 4; ++r) lsum[m][r] += EXP2F(s[r]);
      }
    }
  }
#undef STAGE_KK

  // reduce over the 16 kv-columns held within each 16-lane group
  #pragma unroll
  for (int m = 0; m < 4; ++m)
    #pragma unroll
    for (int r = 0; r < 4; ++r) {
      #pragma unroll
      for (int off = 1; off < 16; off <<= 1)
        lsum[m][r] += __shfl_xor(lsum[m][r], off);
    }
  if (lrow == 0) {
    #pragma unroll
    for (int m = 0; m < 4; ++m)
      #pragma unroll
      for (int r = 0; r < 4; ++r)
        red[wn][wm * 64 + m * 16 + sub * 4 + r] = lsum[m][r];
  }
  __syncthreads();
  if (tid < 128) {
    const float s = red[0][tid] + red[1][tid];
    Linv[((size_t)b * H_ + h) * Q_ + qb + tid] = 1.0f / (s * (float)H_);
  }
}

// ---------------------------------------------------------------------------
// Kernel 6 (pass B): attn[b,i,j] = sum_h 2^s_h(i,j) * Linv[b,h,i]
// GEMM-style: 128x128 output tile, 4 waves 2x2 (64x64), head loop = K loop.
// Both operands double-buffered via global_load_lds (T2 swizzle); per head:
// 32 MFMA/wave -> exp2 * Linv -> persistent fp32 accumulator. Linv in LDS.
// ---------------------------------------------------------------------------
__global__ __launch_bounds__(256, 2) void k_attn_weights(
    const u16* __restrict__ qp, const u16* __restrict__ kp,
    const float* __restrict__ Linv, u16* __restrict__ attn)
{
  const int kv0 = blockIdx.x * 128, qb = blockIdx.y * 128, b = blockIdx.z;
  __shared__ u16 As[2][128 * 64];
  __shared__ u16 Bs[2][128 * 64];
  __shared__ float linv_s[H_][128];
  const int tid = threadIdx.x, lane = tid & 63, w = tid >> 6;
  const int wm = w >> 1, wn = w & 1;
  const int lrow = lane & 15, sub = lane >> 4, lrow7 = lrow & 7;

  // stage Linv for this q-block: 16 heads x 128 rows (8 KB)
  {
    const int hh = tid >> 4, i0 = (tid & 15) * 8;
    const float4 v0 = *reinterpret_cast<const float4*>(
        &Linv[((size_t)b * H_ + hh) * Q_ + qb + i0]);
    const float4 v1 = *reinterpret_cast<const float4*>(
        &Linv[((size_t)b * H_ + hh) * Q_ + qb + i0 + 4]);
    *reinterpret_cast<float4*>(&linv_s[hh][i0]) = v0;
    *reinterpret_cast<float4*>(&linv_s[hh][i0 + 4]) = v1;
  }

#define STAGE_AB(buf, hh)                                                     \
  {                                                                           \
    _Pragma("unroll")                                                         \
    for (int i = 0; i < 4; ++i) {                                             \
      const int c = i * 256 + tid, r = c >> 3, u = (c & 7) ^ (r & 7);         \
      gl_lds16(&qp[((size_t)b * Q_ + qb + r) * D_ + (hh) * 64 + u * 8],       \
               &As[buf][c * 8]);                                              \
      gl_lds16(&kp[((size_t)b * KV_ + kv0 + r) * D_ + (hh) * 64 + u * 8],     \
               &Bs[buf][c * 8]);                                              \
    }                                                                         \
  }

  const f32x4 zero4 = {0.f, 0.f, 0.f, 0.f};
  f32x4 acc[4][4];
  #pragma unroll
  for (int m = 0; m < 4; ++m)
    #pragma unroll
    for (int n = 0; n < 4; ++n) acc[m][n] = zero4;

  STAGE_AB(0, 0);
  for (int h = 0; h < H_; ++h) {
    const int cur = h & 1;
    __syncthreads();                       // buf[cur] staged & visible
    if (h + 1 < H_) STAGE_AB(cur ^ 1, h + 1);
    bf16x8 af[4][2], bf[4][2];
    #pragma unroll
    for (int m = 0; m < 4; ++m) {
      const int rA = wm * 64 + m * 16 + lrow;
      af[m][0] = *(const bf16x8*)&As[cur][rA * 64 + ((sub ^ lrow7) << 3)];
      af[m][1] = *(const bf16x8*)&As[cur][rA * 64 + (((4 + sub) ^ lrow7) << 3)];
    }
    #pragma unroll
    for (int n = 0; n < 4; ++n) {
      const int rB = wn * 64 + n * 16 + lrow;
      bf[n][0] = *(const bf16x8*)&Bs[cur][rB * 64 + ((sub ^ lrow7) << 3)];
      bf[n][1] = *(const bf16x8*)&Bs[cur][rB * 64 + (((4 + sub) ^ lrow7) << 3)];
    }
    f32x4 lv[4];
    #pragma unroll
    for (int m = 0; m < 4; ++m)
      lv[m] = *(const f32x4*)&linv_s[h][wm * 64 + m * 16 + sub * 4];
    #pragma unroll
    for (int m = 0; m < 4; ++m) {
      #pragma unroll
      for (int n = 0; n < 4; ++n) {
        f32x4 s = zero4;
        s = MFMA16(af[m][0], bf[n][0], s);
        s = MFMA16(af[m][1], bf[n][1], s);
        #pragma unroll
        for (int r = 0; r < 4; ++r)
          acc[m][n][r] += EXP2F(s[r]) * lv[m][r];
      }
    }
  }
#undef STAGE_AB

  #pragma unroll
  for (int m = 0; m < 4; ++m) {
    #pragma unroll
    for (int n = 0; n < 4; ++n) {
      const int gcol = kv0 + wn * 64 + n * 16 + lrow;
      #pragma unroll
      for (int r = 0; r < 4; ++r) {
        const int grow = qb + wm * 64 + m * 16 + sub * 4 + r;
        attn[((size_t)b * Q_ + grow) * KV_ + gcol] = f2bf(acc[m][n][r]);
      }
    }
  }
}

// ---------------------------------------------------------------------------
// Launch
// ---------------------------------------------------------------------------
extern "C" void kernel_launch(void* const* d_in, const int* in_sizes, int n_in,
                              void* d_out, int out_size, void* d_ws, size_t ws_size,
                              hipStream_t stream)
{
  (void)in_sizes; (void)n_in; (void)out_size; (void)ws_size;
  const float* query = (const float*)d_in[0];
  const float* key   = (const float*)d_in[1];
  const float* value = (const float*)d_in[2];
  const float* wqn   = (const float*)d_in[3];
  const float* wkn   = (const float*)d_in[4];
  const float* Wq    = (const float*)d_in[5];
  const float* Wk    = (const float*)d_in[6];
  const float* bq    = (const float*)d_in[7];
  const float* bk    = (const float*)d_in[8];
  float* out = (float*)d_out;

  // workspace layout (~46.7 MB; attn aliases the dead qn+kn region)
  char* ws = (char*)d_ws;
  u16* qn   = (u16*)(ws);                 //  8 MiB  (B*Q, D)  bf16
  u16* attn = (u16*)(ws);                 // 16 MiB  (B, Q, KV) bf16 — alias qn+kn
  u16* qp   = (u16*)(ws + 16777216);      //  8 MiB  (B*Q, D)  bf16
  u16* kp   = (u16*)(ws + 25165824);      //  8 MiB  (B*KV, D) bf16
  u16* Wqb  = (u16*)(ws + 33554432);      //  4 MiB  (2, D, D) bf16 (Wq|Wk adjacent)
  u16* vT   = (u16*)(ws + 37748736);      //  8 MiB  (B, D, KV) bf16
  float* Linv = (float*)(ws + 46137344);  // 256 KiB (B, H, Q) fp32
  float* biasbuf = (float*)(ws + 46399488); // 8 KiB (2, D) fp32
  u16* kn = qn + 4194304;

  k_rmsnorm_cast<<<dim3(B_ * Q_ + B_ * KV_), dim3(256), 0, stream>>>(
      query, key, wqn, wkn, qn, kn);
  k_prep_small<<<dim3(2049), dim3(256), 0, stream>>>(Wq, Wk, bq, bk, Wqb, biasbuf);
  k_transpose_cast_v<<<dim3(KV_ / 64, D_ / 64, B_), dim3(256), 0, stream>>>(value, vT);

  // batched projections: z=0 -> qp = (qn@Wq^T + bq)*QSCALE ; z=1 -> kp = kn@Wk^T + bk
  k_gemm_bt<128, 128, true, true>
      <<<dim3(D_ / 128, (B_ * Q_) / 128, 2), dim3(256), 0, stream>>>(
      qn, D_, 4194304, Wqb, D_, 1048576, qp, D_, 4194304, D_, biasbuf);

  k_attn_rowsum<<<dim3(Q_ / 128, H_, B_), dim3(256), 0, stream>>>(qp, kp, Linv);
  k_attn_weights<<<dim3(KV_ / 128, Q_ / 128, B_), dim3(256), 0, stream>>>(qp, kp, Linv, attn);

  // PV: out[b] = attn[b] @ vT[b]^T, 128x64 tiles -> 512 blocks (2/CU)
  k_gemm_bt<128, 64, false, false>
      <<<dim3(D_ / 64, Q_ / 128, B_), dim3(256), 0, stream>>>(
      attn, KV_, (long)Q_ * KV_, vT, KV_, (long)D_ * KV_,
      out, D_, (long)Q_ * D_, KV_, nullptr);
}

// Round 8
// 134.629 us; speedup vs baseline: 1.5604x; 1.0337x over previous
//
#include <hip/hip_runtime.h>

#define B_  2
#define Q_  2048
#define KV_ 2048
#define D_  1024
#define H_  16
#define DH_ 64

// 0.125 * log2(e): folded into qp so attention scores feed exp2 directly
#define QSCALE 0.18033688011112042f

using u16 = unsigned short;
using bf16x8 = __attribute__((ext_vector_type(8))) short;
using f32x4  = __attribute__((ext_vector_type(4))) float;

__device__ __forceinline__ u16 f2bf(float x) {
  unsigned u = __float_as_uint(x);
  u += 0x7fffu + ((u >> 16) & 1u);   // round-to-nearest-even
  return (u16)(u >> 16);
}

__device__ __forceinline__ void gl_lds16(const void* g, void* l) {
  __builtin_amdgcn_global_load_lds(
      (const __attribute__((address_space(1))) void*)g,
      (__attribute__((address_space(3))) void*)l, 16, 0, 0);
}

// counted vmcnt wait: keeps the newest N vmem ops (the just-issued next-tile
// stage) in flight while guaranteeing older stages have landed in LDS.
template<int N> __device__ __forceinline__ void wait_vmcnt() {
  if constexpr (N == 0)      asm volatile("s_waitcnt vmcnt(0)" ::: "memory");
  else if constexpr (N == 4) asm volatile("s_waitcnt vmcnt(4)" ::: "memory");
  else if constexpr (N == 6) asm volatile("s_waitcnt vmcnt(6)" ::: "memory");
  else if constexpr (N == 8) asm volatile("s_waitcnt vmcnt(8)" ::: "memory");
}
__device__ __forceinline__ void barrier_raw() {
  asm volatile("" ::: "memory");
  __builtin_amdgcn_s_barrier();
  asm volatile("" ::: "memory");
}

#define MFMA16(a, b, c) __builtin_amdgcn_mfma_f32_16x16x32_bf16((a), (b), (c), 0, 0, 0)
#define EXP2F(x) __builtin_amdgcn_exp2f(x)

// ---------------------------------------------------------------------------
// Kernel 1 (merged prep): blocks [0,8192): RMSNorm+cast of query|key;
// [8192,10241): Wq|Wk bf16 cast + bias staging; [10241,11265): V transpose.
// All branches are block-uniform; independent work items.
// ---------------------------------------------------------------------------
__global__ __launch_bounds__(256) void k_prep(
    const float* __restrict__ q, const float* __restrict__ k,
    const float* __restrict__ wq, const float* __restrict__ wk,
    const float* __restrict__ Wq, const float* __restrict__ Wk,
    const float* __restrict__ bq, const float* __restrict__ bk,
    const float* __restrict__ v,
    u16* __restrict__ qn, u16* __restrict__ kn,
    u16* __restrict__ Wb, float* __restrict__ biasbuf,
    u16* __restrict__ vT)
{
  __shared__ char smem[64 * 72 * 2];     // union: transpose tile / rmsnorm red
  const int bid = blockIdx.x, t = threadIdx.x;
  if (bid < B_ * Q_ + B_ * KV_) {
    // ---- RMSNorm + bf16 cast ----
    const int row = bid;
    const float* src; const float* w; u16* dst;
    if (row < B_ * Q_) {
      src = q + (size_t)row * D_; w = wq; dst = qn + (size_t)row * D_;
    } else {
      const int r2 = row - B_ * Q_;
      src = k + (size_t)r2 * D_; w = wk; dst = kn + (size_t)r2 * D_;
    }
    float4 vv = reinterpret_cast<const float4*>(src)[t];
    float ss = vv.x * vv.x + vv.y * vv.y + vv.z * vv.z + vv.w * vv.w;
    #pragma unroll
    for (int off = 1; off < 64; off <<= 1) ss += __shfl_xor(ss, off);
    float* red = (float*)smem;
    if ((t & 63) == 0) red[t >> 6] = ss;
    __syncthreads();
    const float tot = red[0] + red[1] + red[2] + red[3];
    const float sc = rsqrtf(tot * (1.0f / D_) + 1.1920929e-07f);
    float4 wv = reinterpret_cast<const float4*>(w)[t];
    ushort4 o;
    o.x = f2bf(vv.x * sc * wv.x);
    o.y = f2bf(vv.y * sc * wv.y);
    o.z = f2bf(vv.z * sc * wv.z);
    o.w = f2bf(vv.w * sc * wv.w);
    reinterpret_cast<ushort4*>(dst)[t] = o;
  } else if (bid < B_ * Q_ + B_ * KV_ + 2049) {
    // ---- Wq|Wk cast + bias staging ----
    const int pb = bid - (B_ * Q_ + B_ * KV_);
    if (pb < 2048) {
      const int i = pb * 256 + t;
      const bool isK = i >= 262144;
      const int j = i & 262143;
      float4 vv = reinterpret_cast<const float4*>(isK ? Wk : Wq)[j];
      ushort4 o;
      o.x = f2bf(vv.x); o.y = f2bf(vv.y); o.z = f2bf(vv.z); o.w = f2bf(vv.w);
      reinterpret_cast<ushort4*>(Wb + (isK ? D_ * D_ : 0))[j] = o;
    } else {
      #pragma unroll
      for (int r = 0; r < 2; ++r) {
        const int i = r * 256 + t;
        float4 vv = (i < 256) ? reinterpret_cast<const float4*>(bq)[i]
                              : reinterpret_cast<const float4*>(bk)[i - 256];
        reinterpret_cast<float4*>(biasbuf)[i] = vv;
      }
    }
  } else {
    // ---- V transpose+cast: (B,KV,D) fp32 -> (B,D,KV) bf16, 64x64 tiles ----
    const int tb = bid - (B_ * Q_ + B_ * KV_ + 2049);   // 0..1023
    const int kv0 = (tb & 31) * 64, d0 = ((tb >> 5) & 15) * 64, b = tb >> 9;
    u16 (*tile)[72] = (u16(*)[72])smem;
    #pragma unroll
    for (int i = 0; i < 16; ++i) {
      const int idx = i * 256 + t, r = idx >> 6, c = idx & 63;
      tile[r][c] = f2bf(v[((size_t)b * KV_ + kv0 + r) * D_ + d0 + c]);
    }
    __syncthreads();
    #pragma unroll
    for (int i = 0; i < 16; ++i) {
      const int idx = i * 256 + t, r = idx >> 6, c = idx & 63;
      vT[((size_t)b * D_ + d0 + r) * KV_ + kv0 + c] = tile[c][r];
    }
  }
}

// ---------------------------------------------------------------------------
// Kernel 4: C = A * B^T (+bias,*scale), bf16 in, fp32 accum. TM x TN tile,
// BK=64, 4 waves 2x2, T2-swizzled LDS, dbuf + COUNTED vmcnt pipeline:
// STAGE(next) issued first each iter; vmcnt(NL) waits only for the previous
// iteration's loads (a full compute phase old) -> stage latency hidden.
// ---------------------------------------------------------------------------
__device__ __forceinline__ int swz_off(int row, int unit) {
  return row * 64 + ((unit ^ (row & 7)) << 3);
}

template<int TM, int TN, bool OUT_BF16, bool PROJ>
__global__ __launch_bounds__(256) void k_gemm_bt(
    const u16* __restrict__ A, int lda, long sA,
    const u16* __restrict__ Bm, int ldb, long sB,
    void* __restrict__ C, int ldc, long sC,
    int K, const float* __restrict__ bias)
{
  constexpr int MR = TM / 32, NR = TN / 32;    // per-wave 16x16 frag repeats
  constexpr int NL = TM / 32 + TN / 32;        // gl_lds16 per thread per stage
  const int bb = blockIdx.z;
  const u16* Ab = A + (size_t)bb * sA;
  const u16* Bb = Bm + (size_t)bb * sB;
  const int row0 = blockIdx.y * TM, col0 = blockIdx.x * TN;
  __shared__ u16 As[2][TM * 64];
  __shared__ u16 Bs[2][TN * 64];
  const int tid = threadIdx.x, lane = tid & 63;
  const int w = tid >> 6, wm = w >> 1, wn = w & 1;
  const int lrow = lane & 15, sub = lane >> 4, lrow7 = lrow & 7;
  const f32x4 zero4 = {0.f, 0.f, 0.f, 0.f};
  f32x4 acc[MR][NR];
  #pragma unroll
  for (int m = 0; m < MR; ++m)
    #pragma unroll
    for (int n = 0; n < NR; ++n) acc[m][n] = zero4;

  const int nk = K >> 6;

#define GEMM_STAGE(buf, kt)                                                   \
  {                                                                           \
    const int k0 = (kt) << 6;                                                 \
    _Pragma("unroll")                                                         \
    for (int i = 0; i < TM / 32; ++i) {                                       \
      const int c = i * 256 + tid, r = c >> 3, u = (c & 7) ^ (r & 7);         \
      gl_lds16(Ab + (size_t)(row0 + r) * lda + k0 + u * 8, &As[buf][c * 8]);  \
    }                                                                         \
    _Pragma("unroll")                                                         \
    for (int i = 0; i < TN / 32; ++i) {                                       \
      const int c = i * 256 + tid, r = c >> 3, u = (c & 7) ^ (r & 7);         \
      gl_lds16(Bb + (size_t)(col0 + r) * ldb + k0 + u * 8, &Bs[buf][c * 8]);  \
    }                                                                         \
  }

  GEMM_STAGE(0, 0);
  int cur = 0;
  for (int kt = 0; kt < nk; ++kt) {
    if (kt + 1 < nk) {
      GEMM_STAGE(cur ^ 1, kt + 1);
      wait_vmcnt<NL>();                  // previous stage done; next in flight
    } else {
      wait_vmcnt<0>();
    }
    barrier_raw();                       // buf[cur] visible to all waves
    #pragma unroll
    for (int ks = 0; ks < 2; ++ks) {
      bf16x8 af[MR], bfr[NR];
      #pragma unroll
      for (int m = 0; m < MR; ++m) {
        const int rA = wm * (TM / 2) + m * 16 + lrow;
        af[m] = *(const bf16x8*)&As[cur][rA * 64 + ((((ks << 2) + sub) ^ lrow7) << 3)];
      }
      #pragma unroll
      for (int n = 0; n < NR; ++n) {
        const int rB = wn * (TN / 2) + n * 16 + lrow;
        bfr[n] = *(const bf16x8*)&Bs[cur][rB * 64 + ((((ks << 2) + sub) ^ lrow7) << 3)];
      }
      #pragma unroll
      for (int m = 0; m < MR; ++m)
        #pragma unroll
        for (int n = 0; n < NR; ++n)
          acc[m][n] = MFMA16(af[m], bfr[n], acc[m][n]);
    }
    barrier_raw();                       // all waves done reading buf[cur]
    cur ^= 1;
  }
#undef GEMM_STAGE

  const int crow = sub * 4, ccol = lane & 15;
  const float scl = (PROJ && bb == 0) ? QSCALE : 1.0f;
  #pragma unroll
  for (int m = 0; m < MR; ++m) {
    #pragma unroll
    for (int n = 0; n < NR; ++n) {
      const int gcol = col0 + wn * (TN / 2) + n * 16 + ccol;
      const float badd = PROJ ? bias[bb * 1024 + gcol] : 0.0f;
      #pragma unroll
      for (int r = 0; r < 4; ++r) {
        const int grow = row0 + wm * (TM / 2) + m * 16 + crow + r;
        const float val = (acc[m][n][r] + badd) * scl;
        if (OUT_BF16)
          ((u16*)C)[(size_t)bb * sC + (size_t)grow * ldc + gcol] = f2bf(val);
        else
          ((float*)C)[(size_t)bb * sC + (size_t)grow * ldc + gcol] = val;
      }
    }
  }
}

// ---------------------------------------------------------------------------
// Kernel 5 (pass A): Linv[b,h,i] = 1 / (H * sum_j 2^s(i,j))   (qp pre-scaled)
// GEMM-style: block = (128 q-rows, head, batch), 4 waves 2x2 (64q x 64kv).
// Aq staged once; K tiles dbuf + counted vmcnt; shuffle+LDS reduce at end.
// ---------------------------------------------------------------------------
__global__ __launch_bounds__(256) void k_attn_rowsum(
    const u16* __restrict__ qp, const u16* __restrict__ kp,
    float* __restrict__ Linv)
{
  const int qb = blockIdx.x * 128, h = blockIdx.y, b = blockIdx.z;
  __shared__ u16 Aq[128 * 64];
  __shared__ u16 Kk[2][128 * 64];
  __shared__ float red[2][128];
  const int tid = threadIdx.x, lane = tid & 63, w = tid >> 6;
  const int wm = w >> 1, wn = w & 1;
  const int lrow = lane & 15, sub = lane >> 4, lrow7 = lrow & 7;

  // stage Aq once (swizzled source)
  #pragma unroll
  for (int i = 0; i < 4; ++i) {
    const int c = i * 256 + tid, r = c >> 3, u = (c & 7) ^ (r & 7);
    gl_lds16(&qp[((size_t)b * Q_ + qb + r) * D_ + h * 64 + u * 8], &Aq[c * 8]);
  }

#define STAGE_KK(buf, kvt)                                                    \
  {                                                                           \
    _Pragma("unroll")                                                         \
    for (int i = 0; i < 4; ++i) {                                             \
      const int c = i * 256 + tid, r = c >> 3, u = (c & 7) ^ (r & 7);         \
      gl_lds16(&kp[((size_t)b * KV_ + (kvt) * 128 + r) * D_ + h * 64 + u * 8],\
               &Kk[buf][c * 8]);                                              \
    }                                                                         \
  }

  STAGE_KK(0, 0);
  const f32x4 zero4 = {0.f, 0.f, 0.f, 0.f};
  float lsum[4][4];
  #pragma unroll
  for (int m = 0; m < 4; ++m)
    #pragma unroll
    for (int r = 0; r < 4; ++r) lsum[m][r] = 0.f;
  bf16x8 af[4][2];

  for (int kvt = 0; kvt < KV_ / 128; ++kvt) {
    const int cur = kvt & 1;
    if (kvt + 1 < KV_ / 128) {
      STAGE_KK(cur ^ 1, kvt + 1);
      wait_vmcnt<4>();                   // Aq + Kk[cur] landed; next in flight
    } else {
      wait_vmcnt<0>();
    }
    barrier_raw();
    if (kvt == 0) {
      #pragma unroll
      for (int m = 0; m < 4; ++m) {
        const int rA = wm * 64 + m * 16 + lrow;
        af[m][0] = *(const bf16x8*)&Aq[rA * 64 + ((sub ^ lrow7) << 3)];
        af[m][1] = *(const bf16x8*)&Aq[rA * 64 + (((4 + sub) ^ lrow7) << 3)];
      }
    }
    bf16x8 bf[4][2];
    #pragma unroll
    for (int n = 0; n < 4; ++n) {
      const int rB = wn * 64 + n * 16 + lrow;
      bf[n][0] = *(const bf16x8*)&Kk[cur][rB * 64 + ((sub ^ lrow7) << 3)];
      bf[n][1] = *(const bf16x8*)&Kk[cur][rB * 64 + (((4 + sub) ^ lrow7) << 3)];
    }
    #pragma unroll
    for (int m = 0; m < 4; ++m) {
      #pragma unroll
      for (int n = 0; n < 4; ++n) {
        f32x4 s = zero4;
        s = MFMA16(af[m][0], bf[n][0], s);
        s = MFMA16(af[m][1], bf[n][1], s);
        #pragma unroll
        for (int r = 0; r < 4; ++r) lsum[m][r] += EXP2F(s[r]);
      }
    }
    barrier_raw();
  }
#undef STAGE_KK

  // reduce over the 16 kv-columns held within each 16-lane group
  #pragma unroll
  for (int m = 0; m < 4; ++m)
    #pragma unroll
    for (int r = 0; r < 4; ++r) {
      #pragma unroll
      for (int off = 1; off < 16; off <<= 1)
        lsum[m][r] += __shfl_xor(lsum[m][r], off);
    }
  if (lrow == 0) {
    #pragma unroll
    for (int m = 0; m < 4; ++m)
      #pragma unroll
      for (int r = 0; r < 4; ++r)
        red[wn][wm * 64 + m * 16 + sub * 4 + r] = lsum[m][r];
  }
  __syncthreads();
  if (tid < 128) {
    const float s = red[0][tid] + red[1][tid];
    Linv[((size_t)b * H_ + h) * Q_ + qb + tid] = 1.0f / (s * (float)H_);
  }
}

// ---------------------------------------------------------------------------
// Kernel 6 (pass B): attn[b,i,j] = sum_h 2^s_h(i,j) * Linv[b,h,i]
// GEMM-style: 128x128 output tile, 4 waves 2x2, head loop = K loop.
// Both operands dbuf'd via global_load_lds (T2 swizzle) + counted vmcnt.
// ---------------------------------------------------------------------------
__global__ __launch_bounds__(256, 2) void k_attn_weights(
    const u16* __restrict__ qp, const u16* __restrict__ kp,
    const float* __restrict__ Linv, u16* __restrict__ attn)
{
  const int kv0 = blockIdx.x * 128, qb = blockIdx.y * 128, b = blockIdx.z;
  __shared__ u16 As[2][128 * 64];
  __shared__ u16 Bs[2][128 * 64];
  __shared__ float linv_s[H_][128];
  const int tid = threadIdx.x, lane = tid & 63, w = tid >> 6;
  const int wm = w >> 1, wn = w & 1;
  const int lrow = lane & 15, sub = lane >> 4, lrow7 = lrow & 7;

  // stage Linv for this q-block: 16 heads x 128 rows (8 KB)
  {
    const int hh = tid >> 4, i0 = (tid & 15) * 8;
    const float4 v0 = *reinterpret_cast<const float4*>(
        &Linv[((size_t)b * H_ + hh) * Q_ + qb + i0]);
    const float4 v1 = *reinterpret_cast<const float4*>(
        &Linv[((size_t)b * H_ + hh) * Q_ + qb + i0 + 4]);
    *reinterpret_cast<float4*>(&linv_s[hh][i0]) = v0;
    *reinterpret_cast<float4*>(&linv_s[hh][i0 + 4]) = v1;
  }

#define STAGE_AB(buf, hh)                                                     \
  {                                                                           \
    _Pragma("unroll")                                                         \
    for (int i = 0; i < 4; ++i) {                                             \
      const int c = i * 256 + tid, r = c >> 3, u = (c & 7) ^ (r & 7);         \
      gl_lds16(&qp[((size_t)b * Q_ + qb + r) * D_ + (hh) * 64 + u * 8],       \
               &As[buf][c * 8]);                                              \
      gl_lds16(&kp[((size_t)b * KV_ + kv0 + r) * D_ + (hh) * 64 + u * 8],     \
               &Bs[buf][c * 8]);                                              \
    }                                                                         \
  }

  const f32x4 zero4 = {0.f, 0.f, 0.f, 0.f};
  f32x4 acc[4][4];
  #pragma unroll
  for (int m = 0; m < 4; ++m)
    #pragma unroll
    for (int n = 0; n < 4; ++n) acc[m][n] = zero4;

  STAGE_AB(0, 0);
  for (int h = 0; h < H_; ++h) {
    const int cur = h & 1;
    if (h + 1 < H_) {
      STAGE_AB(cur ^ 1, h + 1);
      wait_vmcnt<8>();                   // head h staged; head h+1 in flight
    } else {
      wait_vmcnt<0>();
    }
    barrier_raw();
    bf16x8 af[4][2], bf[4][2];
    #pragma unroll
    for (int m = 0; m < 4; ++m) {
      const int rA = wm * 64 + m * 16 + lrow;
      af[m][0] = *(const bf16x8*)&As[cur][rA * 64 + ((sub ^ lrow7) << 3)];
      af[m][1] = *(const bf16x8*)&As[cur][rA * 64 + (((4 + sub) ^ lrow7) << 3)];
    }
    #pragma unroll
    for (int n = 0; n < 4; ++n) {
      const int rB = wn * 64 + n * 16 + lrow;
      bf[n][0] = *(const bf16x8*)&Bs[cur][rB * 64 + ((sub ^ lrow7) << 3)];
      bf[n][1] = *(const bf16x8*)&Bs[cur][rB * 64 + (((4 + sub) ^ lrow7) << 3)];
    }
    f32x4 lv[4];
    #pragma unroll
    for (int m = 0; m < 4; ++m)
      lv[m] = *(const f32x4*)&linv_s[h][wm * 64 + m * 16 + sub * 4];
    #pragma unroll
    for (int m = 0; m < 4; ++m) {
      #pragma unroll
      for (int n = 0; n < 4; ++n) {
        f32x4 s = zero4;
        s = MFMA16(af[m][0], bf[n][0], s);
        s = MFMA16(af[m][1], bf[n][1], s);
        #pragma unroll
        for (int r = 0; r < 4; ++r)
          acc[m][n][r] += EXP2F(s[r]) * lv[m][r];
      }
    }
    barrier_raw();
  }
#undef STAGE_AB

  #pragma unroll
  for (int m = 0; m < 4; ++m) {
    #pragma unroll
    for (int n = 0; n < 4; ++n) {
      const int gcol = kv0 + wn * 64 + n * 16 + lrow;
      #pragma unroll
      for (int r = 0; r < 4; ++r) {
        const int grow = qb + wm * 64 + m * 16 + sub * 4 + r;
        attn[((size_t)b * Q_ + grow) * KV_ + gcol] = f2bf(acc[m][n][r]);
      }
    }
  }
}

// ---------------------------------------------------------------------------
// Launch
// ---------------------------------------------------------------------------
extern "C" void kernel_launch(void* const* d_in, const int* in_sizes, int n_in,
                              void* d_out, int out_size, void* d_ws, size_t ws_size,
                              hipStream_t stream)
{
  (void)in_sizes; (void)n_in; (void)out_size; (void)ws_size;
  const float* query = (const float*)d_in[0];
  const float* key   = (const float*)d_in[1];
  const float* value = (const float*)d_in[2];
  const float* wqn   = (const float*)d_in[3];
  const float* wkn   = (const float*)d_in[4];
  const float* Wq    = (const float*)d_in[5];
  const float* Wk    = (const float*)d_in[6];
  const float* bq    = (const float*)d_in[7];
  const float* bk    = (const float*)d_in[8];
  float* out = (float*)d_out;

  // workspace layout (~46.7 MB; attn aliases the dead qn+kn region)
  char* ws = (char*)d_ws;
  u16* qn   = (u16*)(ws);                 //  8 MiB  (B*Q, D)  bf16
  u16* attn = (u16*)(ws);                 // 16 MiB  (B, Q, KV) bf16 — alias qn+kn
  u16* qp   = (u16*)(ws + 16777216);      //  8 MiB  (B*Q, D)  bf16
  u16* kp   = (u16*)(ws + 25165824);      //  8 MiB  (B*KV, D) bf16
  u16* Wqb  = (u16*)(ws + 33554432);      //  4 MiB  (2, D, D) bf16 (Wq|Wk adjacent)
  u16* vT   = (u16*)(ws + 37748736);      //  8 MiB  (B, D, KV) bf16
  float* Linv = (float*)(ws + 46137344);  // 256 KiB (B, H, Q) fp32
  float* biasbuf = (float*)(ws + 46399488); // 8 KiB (2, D) fp32
  u16* kn = qn + 4194304;

  // merged prep: rmsnorm (8192) + Wcast/bias (2049) + V transpose (1024)
  k_prep<<<dim3(B_ * Q_ + B_ * KV_ + 2049 + 1024), dim3(256), 0, stream>>>(
      query, key, wqn, wkn, Wq, Wk, bq, bk, value, qn, kn, Wqb, biasbuf, vT);

  // batched projections: z=0 -> qp = (qn@Wq^T + bq)*QSCALE ; z=1 -> kp = kn@Wk^T + bk
  k_gemm_bt<128, 128, true, true>
      <<<dim3(D_ / 128, (B_ * Q_) / 128, 2), dim3(256), 0, stream>>>(
      qn, D_, 4194304, Wqb, D_, 1048576, qp, D_, 4194304, D_, biasbuf);

  k_attn_rowsum<<<dim3(Q_ / 128, H_, B_), dim3(256), 0, stream>>>(qp, kp, Linv);
  k_attn_weights<<<dim3(KV_ / 128, Q_ / 128, B_), dim3(256), 0, stream>>>(qp, kp, Linv, attn);

  // PV: out[b] = attn[b] @ vT[b]^T, 128x64 tiles -> 512 blocks (2/CU)
  k_gemm_bt<128, 64, false, false>
      <<<dim3(D_ / 64, Q_ / 128, B_), dim3(256), 0, stream>>>(
      attn, KV_, (long)Q_ * KV_, vT, KV_, (long)D_ * KV_,
      out, D_, (long)Q_ * D_, KV_, nullptr);
}